// Round 5
// baseline (394.237 us; speedup 1.0000x reference)
//
#include <hip/hip_runtime.h>
#include <math.h>

// ---------------------------------------------------------------------------
// AttentionNet round 14: depth-2 prefetch, coarse phases, 2 blocks/CU.
// Session evidence: r9 (depth-1 serial, 3-4 blk) = 336.6, r11 (depth-2 FINE
// phases, 1 blk) = 357.6, r12 (depth-1 dbuf, 2 blk) = 341.8, r13 (+XCD swz)
// = 350.9. All big GEMMs ~850 GF/s with every pipe idle (r11: Mfma 14 /
// VALU 16 / HBM 14 / Occ 20). Cycle model that fits: depth-1 prefetch
// distance (~700 cy) < L3 load latency (~600-900 cy, inputs produced by the
// previous dispatch) -> every tile pays a drain stall, and co-resident
// blocks phase-lock on the shared VMEM path so TLP doesn't cover it:
// (900 + 3x700) x 8 tiles x 4 gens = 96k cy = 40 us == observed.
// Fix (untried quadrant): prefetch distance 2 tiles (1400 cy > latency) with
// COARSE phasing (1 barrier + 1 counted vmcnt(6) per K-tile, never 0 until
// tail) and 2 blocks/CU: BM=64 x BN=128, 256 thr / 4 waves, acc[4][2],
// TRIPLE-buffered LDS 3x(8K+16K)=72 KB. Staging/reader swizzle and all five
// epilogues are verbatim from the verified r12 kernel (just 256 thr, BN=128).
// XCD swizzle removed (r13: -9 us, L3-fit regime). Wqk precompute stays on
// the old 128x128 kernel. 12 dispatches. Scales unchanged.
// ---------------------------------------------------------------------------

typedef __attribute__((ext_vector_type(8))) int i32x8;
typedef __attribute__((ext_vector_type(4))) int i32x4;
typedef __attribute__((ext_vector_type(4))) float f32x4;
typedef unsigned char u8;
typedef unsigned int u32;

#define EPI_F8 1
#define EPI_RV 2
#define EPI_EXP 3
#define EPI_PV 4
#define EPI_EXPF32 5

__device__ __forceinline__ void gload_lds16(const void* g, void* l) {
    __builtin_amdgcn_global_load_lds(
        (const __attribute__((address_space(1))) void*)g,
        (__attribute__((address_space(3))) void*)l, 16, 0, 0);
}

__device__ __forceinline__ u8 cvt_f8(float v) {
    return (u8)(__builtin_amdgcn_cvt_pk_fp8_f32(v, v, 0, false) & 0xFF);
}

__device__ __forceinline__ u32 pack_f8x4(float v0, float v1, float v2, float v3) {
    int p01 = __builtin_amdgcn_cvt_pk_fp8_f32(v0, v1, 0, false);
    int p23 = __builtin_amdgcn_cvt_pk_fp8_f32(v2, v3, 0, false);
    return (u32)(p01 & 0xFFFF) | ((u32)p23 << 16);
}

#define MFMA_F8(a, b, c) \
    __builtin_amdgcn_mfma_scale_f32_16x16x128_f8f6f4( \
        (a), (b), (c), 0, 0, 0, 0x7F7F7F7F, 0, 0x7F7F7F7F)

// ---------------------------------------------------------------------------
// Old 128x128 kernel — retained for the tiny Wqk precompute GEMM only.
// ---------------------------------------------------------------------------
template <int EPI>
__global__ __launch_bounds__(256) void gemm_fp8(
    const u8* __restrict__ A, const u8* __restrict__ B,
    void* __restrict__ C0, void* __restrict__ C1, void* __restrict__ C2,
    int K, int ldA, int ldB, int ldC,
    long long bsA, long long bsB, long long bsC, float alpha, float beta)
{
    __shared__ u8 sA[128 * 128];
    __shared__ u8 sB[128 * 128];

    const int tid = threadIdx.x;
    const int wave = tid >> 6, lane = tid & 63;
    const int wm = wave >> 1, wn = wave & 1;
    const int m0 = blockIdx.y * 128, n0 = blockIdx.x * 128;
    const long long z = blockIdx.z;

    const u8* pA = A + z * bsA;
    const u8* pB = B + z * bsB;

    int blkid[4], rs_[4], cs16[4];
#pragma unroll
    for (int i = 0; i < 4; i++) {
        blkid[i] = wave * 256 + i * 64 + lane;
        rs_[i] = blkid[i] >> 3;
        cs16[i] = ((blkid[i] & 7) ^ (rs_[i] & 7)) * 16;
    }

    f32x4 acc[4][4] = {};
    const int fr = lane & 15, fc2 = (lane >> 4) * 2;

    for (int k0 = 0; k0 < K; k0 += 128) {
#pragma unroll
        for (int i = 0; i < 4; i++) {
            gload_lds16(pA + (long long)(m0 + rs_[i]) * ldA + k0 + cs16[i],
                        sA + blkid[i] * 16);
            gload_lds16(pB + (long long)(n0 + rs_[i]) * ldB + k0 + cs16[i],
                        sB + blkid[i] * 16);
        }
        __syncthreads();

        i32x8 a[4], b[4];
#pragma unroll
        for (int i = 0; i < 4; i++) {
            const int row = wm * 64 + i * 16 + fr;
            const int sw = row & 7;
            i32x4 lo = *(const i32x4*)(sA + row * 128 + ((fc2 + 0) ^ sw) * 16);
            i32x4 hi = *(const i32x4*)(sA + row * 128 + ((fc2 + 1) ^ sw) * 16);
            a[i] = __builtin_shufflevector(lo, hi, 0, 1, 2, 3, 4, 5, 6, 7);
        }
#pragma unroll
        for (int j = 0; j < 4; j++) {
            const int row = wn * 64 + j * 16 + fr;
            const int sw = row & 7;
            i32x4 lo = *(const i32x4*)(sB + row * 128 + ((fc2 + 0) ^ sw) * 16);
            i32x4 hi = *(const i32x4*)(sB + row * 128 + ((fc2 + 1) ^ sw) * 16);
            b[j] = __builtin_shufflevector(lo, hi, 0, 1, 2, 3, 4, 5, 6, 7);
        }
#pragma unroll
        for (int i = 0; i < 4; i++)
#pragma unroll
            for (int j = 0; j < 4; j++)
                acc[i][j] = MFMA_F8(a[i], b[j], acc[i][j]);
        __syncthreads();
    }

    const int col = lane & 15;
    const int rbase = (lane >> 4) * 4;

    if (EPI == EPI_F8) {
#pragma unroll
        for (int j = 0; j < 4; j++) {
            const int Cq = n0 + wn * 64 + j * 16 + col;
#pragma unroll
            for (int i = 0; i < 4; i++) {
                const int R0 = m0 + wm * 64 + i * 16 + rbase;
                u8* C = (u8*)C0 + z * bsC;
                *(u32*)(C + (long long)Cq * ldC + R0) =
                    pack_f8x4(acc[i][j][0] * alpha, acc[i][j][1] * alpha,
                              acc[i][j][2] * alpha, acc[i][j][3] * alpha);
            }
        }
    }
    (void)beta; (void)C1; (void)C2;
}

// ---------------------------------------------------------------------------
// gemm64t: BM=64 (A-rows), BN=128 (B-rows), BK=128 bytes. 256 thr / 4 waves,
// each wave owns a 64x32 output (acc[4][2]). TRIPLE-buffered LDS:
// 3 x (A 8K + B 16K) = 72 KiB -> 2 blocks/CU. Depth-2 prefetch, coarse
// phases: STAGE(t+2) -> compute(t) -> s_waitcnt vmcnt(6) -> s_barrier.
// vmcnt(6) leaves only tile (t+2)'s 6 loads outstanding => tile t+1 is
// resident at the barrier; buffer (t%3) is overwritten only by STAGE(t+3),
// issued after the barrier that ends iteration t. Never drains to 0 until
// the tail. C = epilogue(alpha * (A @ B^T)), output [B-row][A-row].
// Requires K % 128 == 0 and K/128 >= 2.
// ---------------------------------------------------------------------------
template <int EPI>
__global__ __launch_bounds__(256, 2) void gemm64t(
    const u8* __restrict__ A, const u8* __restrict__ B,
    void* __restrict__ C0, void* __restrict__ C1, void* __restrict__ C2,
    int K, int ldA, int ldB, int ldC,
    long long bsA, long long bsB, long long bsC, float alpha, float beta)
{
    __shared__ __align__(16) u8 sA[3][64 * 128];    // 3 x 8 KiB
    __shared__ __align__(16) u8 sB[3][128 * 128];   // 3 x 16 KiB

    const int tid = threadIdx.x;
    const int wave = tid >> 6, lane = tid & 63;
    const int m0 = blockIdx.y * 64, n0 = blockIdx.x * 128;
    const long long z = blockIdx.z;

    const u8* pA = A + z * bsA;
    const u8* pB = B + z * bsB;

    // Staging: 2 A-chunks + 4 B-chunks (16 B each) per thread per K-tile.
    // LDS slot (row, s) holds global chunk s ^ (row & 7); LDS linear in id
    // (global_load_lds dst = wave-uniform base + lane*16); swizzle applied
    // on the per-lane GLOBAL source address.
    long long offA[2]; int dstA[2];
#pragma unroll
    for (int l = 0; l < 2; l++) {
        const int id = l * 256 + tid;
        const int r = id >> 3, c = (id & 7) ^ (r & 7);
        offA[l] = (long long)(m0 + r) * ldA + c * 16;
        dstA[l] = id * 16;
    }
    long long offB[4]; int dstB[4];
#pragma unroll
    for (int l = 0; l < 4; l++) {
        const int id = l * 256 + tid;
        const int r = id >> 3, c = (id & 7) ^ (r & 7);
        offB[l] = (long long)(n0 + r) * ldB + c * 16;
        dstB[l] = id * 16;
    }

    f32x4 acc[4][2] = {};
    const int fr = lane & 15, fc2 = (lane >> 4) * 2;
    const int NT = K >> 7;

    auto STAGE = [&](int t) {
        const long long kb = (long long)t << 7;
        const int buf = t % 3;
#pragma unroll
        for (int l = 0; l < 2; l++)
            gload_lds16(pA + offA[l] + kb, &sA[buf][dstA[l]]);
#pragma unroll
        for (int l = 0; l < 4; l++)
            gload_lds16(pB + offB[l] + kb, &sB[buf][dstB[l]]);
    };

    // Prologue: tiles 0 and 1 in flight (12 loads); vmcnt(6) -> tile 0
    // complete, tile 1's 6 stay outstanding.
    STAGE(0);
    STAGE(1);
    asm volatile("s_waitcnt vmcnt(6)" ::: "memory");
    __builtin_amdgcn_sched_barrier(0);
    __builtin_amdgcn_s_barrier();
    __builtin_amdgcn_sched_barrier(0);

    for (int t = 0; t < NT; ++t) {
        if (t + 2 < NT) STAGE(t + 2);

        const int buf = t % 3;
        i32x8 a[4], b[2];
#pragma unroll
        for (int i = 0; i < 4; i++) {
            const int row = i * 16 + fr;
            const int sw = row & 7;
            const u8* p = &sA[buf][row * 128];
            i32x4 lo = *(const i32x4*)(p + ((fc2 + 0) ^ sw) * 16);
            i32x4 hi = *(const i32x4*)(p + ((fc2 + 1) ^ sw) * 16);
            a[i] = __builtin_shufflevector(lo, hi, 0, 1, 2, 3, 4, 5, 6, 7);
        }
#pragma unroll
        for (int j = 0; j < 2; j++) {
            const int row = wave * 32 + j * 16 + fr;
            const int sw = row & 7;
            const u8* p = &sB[buf][row * 128];
            i32x4 lo = *(const i32x4*)(p + ((fc2 + 0) ^ sw) * 16);
            i32x4 hi = *(const i32x4*)(p + ((fc2 + 1) ^ sw) * 16);
            b[j] = __builtin_shufflevector(lo, hi, 0, 1, 2, 3, 4, 5, 6, 7);
        }
#pragma unroll
        for (int i = 0; i < 4; i++)
#pragma unroll
            for (int j = 0; j < 2; j++)
                acc[i][j] = MFMA_F8(a[i], b[j], acc[i][j]);

        // Counted publish: tile t+1 resident after this; only tile (t+2)'s
        // 6 loads remain in flight across the barrier.
        if (t + 2 < NT)
            asm volatile("s_waitcnt vmcnt(6)" ::: "memory");
        else
            asm volatile("s_waitcnt vmcnt(0)" ::: "memory");
        __builtin_amdgcn_sched_barrier(0);
        __builtin_amdgcn_s_barrier();
        __builtin_amdgcn_sched_barrier(0);
    }

    // ------------------------- epilogues (r12-verified) --------------------
    // Per-wave output: B-rows [wave*32, wave*32+32), A-rows [m0, m0+64).
    const int col = lane & 15;         // B-row offset within 16-tile
    const int rbase = (lane >> 4) * 4; // first of 4 consecutive A-rows

    if (EPI == EPI_EXP) {
        u8* P = (u8*)C0 + z * bsC;
        float* rsum = (float*)C1 + z * 2048;
#pragma unroll
        for (int j = 0; j < 2; j++) {
            const int Cq = n0 + wave * 32 + j * 16 + col;
            float part = 0.f;
#pragma unroll
            for (int i = 0; i < 4; i++) {
                const int R0 = m0 + i * 16 + rbase;
                float e0 = __expf(acc[i][j][0] * alpha);
                float e1 = __expf(acc[i][j][1] * alpha);
                float e2 = __expf(acc[i][j][2] * alpha);
                float e3 = __expf(acc[i][j][3] * alpha);
                part += (e0 + e1) + (e2 + e3);
                *(u32*)(P + (long long)Cq * ldC + R0) =
                    pack_f8x4(e0 * 0.0625f, e1 * 0.0625f,
                              e2 * 0.0625f, e3 * 0.0625f);
            }
            part += __shfl_xor(part, 16);
            part += __shfl_xor(part, 32);
            if (lane < 16) atomicAdd(&rsum[Cq], part);
        }
        return;
    }

    if (EPI == EPI_EXPF32) {
        float* Cw = (float*)C0;
        float* rsum = (float*)C1;
#pragma unroll
        for (int j = 0; j < 2; j++) {
            const int Cq = n0 + wave * 32 + j * 16 + col;
            float part = 0.f;
#pragma unroll
            for (int i = 0; i < 4; i++) {
                const int R0 = m0 + i * 16 + rbase;
                float4 e;
                e.x = __expf(acc[i][j][0] * alpha);
                e.y = __expf(acc[i][j][1] * alpha);
                e.z = __expf(acc[i][j][2] * alpha);
                e.w = __expf(acc[i][j][3] * alpha);
                part += (e.x + e.y) + (e.z + e.w);
                *(float4*)(Cw + (long long)Cq * ldC + R0) = e;
            }
            part += __shfl_xor(part, 16);
            part += __shfl_xor(part, 32);
            if (lane < 16) atomicAdd(&rsum[Cq], part);
        }
        return;
    }

#pragma unroll
    for (int j = 0; j < 2; j++) {
        const int Cq = n0 + wave * 32 + j * 16 + col;
        float inv;
        if (EPI == EPI_PV) {
            const float* rsum = (const float*)C1 + z * 2048;
            inv = alpha / rsum[Cq];
        }
#pragma unroll
        for (int i = 0; i < 4; i++) {
            const int R0 = m0 + i * 16 + rbase;
            if (EPI == EPI_F8) {
                u8* C = (u8*)C0 + z * bsC;
                *(u32*)(C + (long long)Cq * ldC + R0) =
                    pack_f8x4(acc[i][j][0] * alpha, acc[i][j][1] * alpha,
                              acc[i][j][2] * alpha, acc[i][j][3] * alpha);
            } else if (EPI == EPI_PV) {
                u8* C = (u8*)C0 + z * bsC;
                float v[4];
#pragma unroll
                for (int r = 0; r < 4; r++) {
                    float t = acc[i][j][r] * inv;
                    v[r] = (t / (1.f + __expf(-t))) * beta;   // silu * beta
                }
                *(u32*)(C + (long long)Cq * ldC + R0) =
                    pack_f8x4(v[0], v[1], v[2], v[3]);
            } else { // EPI_RV: A-rows 0..1023 -> R (alpha), 1024.. -> V^T (beta)
                const int seg = R0 >> 10;
                const int db = R0 & 1023;
                if (seg == 1) {
                    const int bb = Cq >> 11, tt = Cq & 2047;
                    u8* VTp = (u8*)C2;
#pragma unroll
                    for (int r = 0; r < 4; r++)
                        VTp[(long long)bb * (1024LL * 2048) +
                            (long long)(db + r) * 2048 + tt] =
                            cvt_f8(acc[i][j][r] * beta);
                } else {
                    u8* C = (u8*)C0;
                    *(u32*)(C + (long long)Cq * 1024 + db) =
                        pack_f8x4(acc[i][j][0] * alpha, acc[i][j][1] * alpha,
                                  acc[i][j][2] * alpha, acc[i][j][3] * alpha);
                }
            }
        }
    }
}

// x (8192 blocks, scale 8) + wv1|wv2|fc1|fc2 (1024 blocks each, scale 256)
// -> fp8; blocks 0..23 zero the 3 rsum buffers (24576 floats at rz).
__global__ __launch_bounds__(256) void convert_all(
    const float* x, const float* wv1, const float* wv2, const float* fc1,
    const float* fc2, u8* __restrict__ ax, u8* __restrict__ bproj,
    u8* __restrict__ wfc, float* __restrict__ rz)
{
    const int bid = blockIdx.x;
    if (bid < 24) {
        float4 zero = {0.f, 0.f, 0.f, 0.f};
        *(float4*)(rz + ((long long)bid * 256 + threadIdx.x) * 4) = zero;
    }
    const float* src;
    u8* dst;
    float scale;
    long long i;
    if (bid < 8192) {
        src = x; dst = ax; scale = 8.f;
        i = ((long long)bid * 256 + threadIdx.x) * 4;
    } else {
        const int idx = bid - 8192;
        const int wi = idx >> 10;
        const float* srcs[4] = {wv1, wv2, fc1, fc2};
        u8* dsts[4] = {bproj + (1 << 20), bproj + 3 * (1 << 20),
                       wfc, wfc + (1 << 20)};
        src = srcs[wi]; dst = dsts[wi]; scale = 256.f;
        i = (((long long)(idx & 1023)) * 256 + threadIdx.x) * 4;
    }
    float4 v = *(const float4*)(src + i);
    *(u32*)(dst + i) = pack_f8x4(v.x * scale, v.y * scale,
                                 v.z * scale, v.w * scale);
}

// Transpose+convert wq1,wk1,wq2,wk2 (fp32 [1024][1024]) -> fp8^T * 256.
__global__ __launch_bounds__(256) void convert_t(
    const float* wq1, const float* wk1, const float* wq2, const float* wk2,
    u8* __restrict__ o)
{
    const float* srcs[4] = {wq1, wk1, wq2, wk2};
    const float* src = srcs[blockIdx.y];
    u8* dst = o + (long long)blockIdx.y * (1 << 20);
    const int q0 = (blockIdx.x & 15) * 64, d0 = (blockIdx.x >> 4) * 64;
    const int qq = (threadIdx.x & 15) * 4, dd = (threadIdx.x >> 4) * 4;
    float4 v[4];
#pragma unroll
    for (int s = 0; s < 4; s++)
        v[s] = *(const float4*)(src + (long long)(q0 + qq + s) * 1024 + d0 + dd);
    const float* vf = (const float*)v;
#pragma unroll
    for (int r = 0; r < 4; r++)
        *(u32*)(dst + (long long)(d0 + dd + r) * 1024 + q0 + qq) =
            pack_f8x4(vf[0 * 4 + r] * 256.f, vf[1 * 4 + r] * 256.f,
                      vf[2 * 4 + r] * 256.f, vf[3 * 4 + r] * 256.f);
}

// out[row][c] = e[row][c] / rsum[row]  (1024 cols, fp32)
__global__ __launch_bounds__(256) void normalize_1024(
    const float* __restrict__ e, const float* __restrict__ rsum,
    float* __restrict__ out)
{
    const long long row = blockIdx.x;
    const float inv = 1.0f / rsum[row];
    const float* p = e + row * 1024;
    float* o = out + row * 1024;
    float4 v = *(const float4*)(p + threadIdx.x * 4);
    float4 ov;
    ov.x = v.x * inv; ov.y = v.y * inv; ov.z = v.z * inv; ov.w = v.w * inv;
    *(float4*)(o + threadIdx.x * 4) = ov;
}

extern "C" void kernel_launch(void* const* d_in, const int* in_sizes, int n_in,
                              void* d_out, int out_size, void* d_ws, size_t ws_size,
                              hipStream_t stream)
{
    float* out = (float*)d_out;

    constexpr int Bt = 4, S = 2048, D = 1024;
    constexpr int M = Bt * S;                  // 8192
    const long long MD = (long long)M * D;     // 8,388,608
    const long long DD = (long long)D * D;
    const long long SD = (long long)S * D;
    const long long SS = (long long)S * S;

    // ws: Af 8MB | Bproj 2x2MB | WqT 4x1MB | Wfc 2x1MB | Rf 8MB | VT 8MB |
    // Pf 16MB | Hs 8MB | SC fp32 32MB | rsum0|1|2
    u8* Af = (u8*)d_ws;
    u8* Bproj = Af + MD;                 // [2][2048][1024]: WqkT | wv
    u8* WqT = Bproj + 2 * 2048 * 1024;   // wq1T | wk1T | wq2T | wk2T
    u8* Wfc = WqT + 4 * DD;              // fc1 | fc2
    u8* Rf = Wfc + 2 * DD;
    u8* VT = Rf + MD;
    u8* Pf = VT + MD;
    u8* Hs = Pf + (long long)Bt * SS;
    float* SC = (float*)(Hs + MD);
    float* rsum0 = SC + MD;
    float* rsum1 = rsum0 + M;
    float* rsum2 = rsum1 + M;

    const dim3 blk(256);

    const float SOFT = 0.08838834764831845f; // 1/sqrt(128)
    const float a_d1   = 1.f / 64.f;               // WqkT: 256*256 -> 1024
    const float a_R[2] = {1.f / 512.f, 1.f / 1024.f};
    const float b_V[2] = {1.f / 256.f, 1.f / 64.f};
    const float a_qk[2] = {SOFT / 128.f, SOFT / 65536.f};
    const float a_pv[2] = {2.0f, 1.f / 64.f};
    const float b_pv[2] = {256.f, 65536.f};
    const float a_fc[2] = {256.f / 65536.f, 1.f / 16777216.f};

    convert_all<<<dim3(12288), blk, 0, stream>>>(
        (const float*)d_in[0], (const float*)d_in[3], (const float*)d_in[7],
        (const float*)d_in[4], (const float*)d_in[8], Af, Bproj, Wfc, rsum0);
    convert_t<<<dim3(256, 4), blk, 0, stream>>>(
        (const float*)d_in[1], (const float*)d_in[2], (const float*)d_in[5],
        (const float*)d_in[6], WqT);
    // Bproj[z] rows 0..1023 = WqkT_z = P(A=wqT_z, B=wkT_z), stored scale 1024
    gemm_fp8<EPI_F8><<<dim3(8, 8, 2), blk, 0, stream>>>(
        WqT, WqT + DD, Bproj, nullptr, nullptr, D, D, D, D,
        2 * DD, 2 * DD, (long long)2048 * 1024, a_d1, 0.f);

    const dim3 grv(M / 128, 2048 / 64, 1);     // [R|V] projection (64,32)
    const dim3 gqk(S / 128, S / 64, Bt);       // scores (16,32,4)
    const dim3 gpv(S / 128, D / 64, Bt);       // PV (16,16,4)
    const dim3 gw(M / 128, D / 64, 1);         // fc GEMMs (64,16)

    for (int layer = 0; layer < 2; layer++) {
        const u8* bp = Bproj + (long long)layer * 2048 * 1024;
        const u8* fc = Wfc + (long long)layer * DD;
        float* rsum = layer ? rsum1 : rsum0;

        // R[t][j] (Rf, packed u32) and V^T[b][d][t] (VT, scatter)
        gemm64t<EPI_RV><<<grv, blk, 0, stream>>>(
            bp, Af, Rf, nullptr, VT, D, D, D, D, 0, 0, 0,
            a_R[layer], b_V[layer]);
        // P[z][q][key] = fp8(exp(score)/16); rsum[q] = sum exp.
        gemm64t<EPI_EXP><<<gqk, blk, 0, stream>>>(
            Af, Rf, Pf, rsum, nullptr, D, D, D, S, SD, SD, SS,
            a_qk[layer], 0.f);
        // Hs[token][d] = fp8(silu(P@V / rsum) * b_pv)
        gemm64t<EPI_PV><<<gpv, blk, 0, stream>>>(
            VT, Pf, Hs, rsum, nullptr, S, S, S, D,
            (long long)D * S, SS, SD, a_pv[layer], b_pv[layer]);
        if (layer == 0) {
            gemm64t<EPI_F8><<<gw, blk, 0, stream>>>(
                fc, Hs, Af, nullptr, nullptr, D, D, D, D, 0, 0, 0,
                a_fc[0], 0.f);
        } else {
            gemm64t<EPI_EXPF32><<<gw, blk, 0, stream>>>(
                fc, Hs, SC, rsum2, nullptr, D, D, D, D, 0, 0, 0,
                a_fc[1], 0.f);
        }
    }

    normalize_1024<<<dim3(M), blk, 0, stream>>>(SC, rsum2, out);
}

// Round 6
// 328.527 us; speedup vs baseline: 1.2000x; 1.2000x over previous
//
#include <hip/hip_runtime.h>
#include <math.h>

// ---------------------------------------------------------------------------
// AttentionNet round 15: restore the verified r9 kernel (336.6 us).
// Rounds 10-14 probed every structural axis on the GEMM core — coarse/fine
// pipelining, counted vmcnt depth 1/2, occupancy 1/2/5 blocks/CU, tiles
// 64/128/256, XCD swizzle — and ALL regressed (341-394 us) with identical
// counter profiles (MfmaUtil 13%, VALU 16-20%, HBM 13%, Occ 20%). The
// maximal-TLP simple core below (5 blocks/CU, single-buffered 32KB LDS,
// one vmcnt(0) drain per K-tile) is the measured optimum for this shape
// regime (K=1024, 8 K-tiles/block, 8 serial GEMM rounds). Flash-fusion of
// EXP+PV is register-infeasible at D=1024; fc1-folding needs F on both
// sides of Wqk2 (net ~-6 us, high scale risk). Restoring the floor.
//
// QK^T reassociation: scores = x wq^T wk x^T = (x@Wqk)@x^T with Wqk =
// wq^T wk precomputed per layer. Q/K never materialized: projection = [R|V]
// (N=2048) and the EXP GEMM's key operand is the activation buffer itself.
// GEMM core: 16x16x128 MX-fp8 e4m3, 128x128 tile, XOR-swizzled LDS
// (0 conflicts), global_load_lds(16). 12 dispatches.
// Scales (pow2, exact alpha folds): x*8, w*256 (all), WqkT*1024, R1*16,
// R2*256, V1*8, V2*1024, P=expS/16, Hs1*256, Hs2*65536, h2*256.
// ---------------------------------------------------------------------------

typedef __attribute__((ext_vector_type(8))) int i32x8;
typedef __attribute__((ext_vector_type(4))) int i32x4;
typedef __attribute__((ext_vector_type(4))) float f32x4;
typedef unsigned char u8;
typedef unsigned int u32;

#define EPI_F8 1
#define EPI_RV 2
#define EPI_EXP 3
#define EPI_PV 4
#define EPI_EXPF32 5

__device__ __forceinline__ void gload_lds16(const void* g, void* l) {
    __builtin_amdgcn_global_load_lds(
        (const __attribute__((address_space(1))) void*)g,
        (__attribute__((address_space(3))) void*)l, 16, 0, 0);
}

__device__ __forceinline__ u8 cvt_f8(float v) {
    return (u8)(__builtin_amdgcn_cvt_pk_fp8_f32(v, v, 0, false) & 0xFF);
}

__device__ __forceinline__ u32 pack_f8x4(float v0, float v1, float v2, float v3) {
    int p01 = __builtin_amdgcn_cvt_pk_fp8_f32(v0, v1, 0, false);
    int p23 = __builtin_amdgcn_cvt_pk_fp8_f32(v2, v3, 0, false);
    return (u32)(p01 & 0xFFFF) | ((u32)p23 << 16);
}

// C = epilogue(alpha * (A @ B^T)); A=[MA,K] fp8 (weight/key/VT side),
// B=[NB,K] fp8 (token side), batch=blockIdx.z. K % 128 == 0.
// Output row-major [B-row][A-row]: lane's 4 regs = 4 consecutive A-rows.
template <int EPI>
__global__ __launch_bounds__(256) void gemm_fp8(
    const u8* __restrict__ A, const u8* __restrict__ B,
    void* __restrict__ C0, void* __restrict__ C1, void* __restrict__ C2,
    int K, int ldA, int ldB, int ldC,
    long long bsA, long long bsB, long long bsC, float alpha, float beta)
{
    __shared__ u8 sA[128 * 128];
    __shared__ u8 sB[128 * 128];

    const int tid = threadIdx.x;
    const int wave = tid >> 6, lane = tid & 63;
    const int wm = wave >> 1, wn = wave & 1;
    const int m0 = blockIdx.y * 128, n0 = blockIdx.x * 128;
    const long long z = blockIdx.z;

    const u8* pA = A + z * bsA;
    const u8* pB = B + z * bsB;

    // Tile = 128 rows x 8 16B-chunks. LDS chunk (row,c) holds global chunk
    // c ^ (row&7). global_load_lds dst must be wave-uniform base + lane*16.
    int blkid[4], rs_[4], cs16[4];
#pragma unroll
    for (int i = 0; i < 4; i++) {
        blkid[i] = wave * 256 + i * 64 + lane;
        rs_[i] = blkid[i] >> 3;
        cs16[i] = ((blkid[i] & 7) ^ (rs_[i] & 7)) * 16;
    }

    f32x4 acc[4][4] = {};
    const int fr = lane & 15, fc2 = (lane >> 4) * 2;

    for (int k0 = 0; k0 < K; k0 += 128) {
#pragma unroll
        for (int i = 0; i < 4; i++) {
            gload_lds16(pA + (long long)(m0 + rs_[i]) * ldA + k0 + cs16[i],
                        sA + blkid[i] * 16);
            gload_lds16(pB + (long long)(n0 + rs_[i]) * ldB + k0 + cs16[i],
                        sB + blkid[i] * 16);
        }
        __syncthreads();

        i32x8 a[4], b[4];
#pragma unroll
        for (int i = 0; i < 4; i++) {
            const int row = wm * 64 + i * 16 + fr;
            const int sw = row & 7;
            i32x4 lo = *(const i32x4*)(sA + row * 128 + ((fc2 + 0) ^ sw) * 16);
            i32x4 hi = *(const i32x4*)(sA + row * 128 + ((fc2 + 1) ^ sw) * 16);
            a[i] = __builtin_shufflevector(lo, hi, 0, 1, 2, 3, 4, 5, 6, 7);
        }
#pragma unroll
        for (int j = 0; j < 4; j++) {
            const int row = wn * 64 + j * 16 + fr;
            const int sw = row & 7;
            i32x4 lo = *(const i32x4*)(sB + row * 128 + ((fc2 + 0) ^ sw) * 16);
            i32x4 hi = *(const i32x4*)(sB + row * 128 + ((fc2 + 1) ^ sw) * 16);
            b[j] = __builtin_shufflevector(lo, hi, 0, 1, 2, 3, 4, 5, 6, 7);
        }
#pragma unroll
        for (int i = 0; i < 4; i++)
#pragma unroll
            for (int j = 0; j < 4; j++)
                acc[i][j] = __builtin_amdgcn_mfma_scale_f32_16x16x128_f8f6f4(
                    a[i], b[j], acc[i][j], 0 /*A=e4m3*/, 0 /*B=e4m3*/,
                    0, 0x7F7F7F7F, 0, 0x7F7F7F7F);
        __syncthreads();
    }

    const int col = lane & 15;       // B-row offset within 16-tile
    const int rbase = (lane >> 4) * 4; // first of 4 consecutive A-rows

    if (EPI == EPI_EXP) {
        // P[z][q][key] = fp8(exp(acc*alpha)/16) packed u32; rsum[q] += sum e
        u8* P = (u8*)C0 + z * bsC;
        float* rsum = (float*)C1 + z * 2048;
#pragma unroll
        for (int j = 0; j < 4; j++) {
            const int Cq = n0 + wn * 64 + j * 16 + col;
            float part = 0.f;
#pragma unroll
            for (int i = 0; i < 4; i++) {
                const int R0 = m0 + wm * 64 + i * 16 + rbase;
                float e0 = __expf(acc[i][j][0] * alpha);
                float e1 = __expf(acc[i][j][1] * alpha);
                float e2 = __expf(acc[i][j][2] * alpha);
                float e3 = __expf(acc[i][j][3] * alpha);
                part += (e0 + e1) + (e2 + e3);
                *(u32*)(P + (long long)Cq * ldC + R0) =
                    pack_f8x4(e0 * 0.0625f, e1 * 0.0625f,
                              e2 * 0.0625f, e3 * 0.0625f);
            }
            part += __shfl_xor(part, 16);
            part += __shfl_xor(part, 32);
            if (lane < 16) atomicAdd(&rsum[Cq], part);
        }
        return;
    }

    if (EPI == EPI_EXPF32) {
        // E[token][class] = exp(acc*alpha) float4; rsum[token] += sum
        float* Cw = (float*)C0;
        float* rsum = (float*)C1;
#pragma unroll
        for (int j = 0; j < 4; j++) {
            const int Cq = n0 + wn * 64 + j * 16 + col;
            float part = 0.f;
#pragma unroll
            for (int i = 0; i < 4; i++) {
                const int R0 = m0 + wm * 64 + i * 16 + rbase;
                float4 e;
                e.x = __expf(acc[i][j][0] * alpha);
                e.y = __expf(acc[i][j][1] * alpha);
                e.z = __expf(acc[i][j][2] * alpha);
                e.w = __expf(acc[i][j][3] * alpha);
                part += (e.x + e.y) + (e.z + e.w);
                *(float4*)(Cw + (long long)Cq * ldC + R0) = e;
            }
            part += __shfl_xor(part, 16);
            part += __shfl_xor(part, 32);
            if (lane < 16) atomicAdd(&rsum[Cq], part);
        }
        return;
    }

#pragma unroll
    for (int j = 0; j < 4; j++) {
        const int Cq = n0 + wn * 64 + j * 16 + col;
        float inv;
        if (EPI == EPI_PV) {
            const float* rsum = (const float*)C1 + z * 2048;
            inv = alpha / rsum[Cq];
        }
#pragma unroll
        for (int i = 0; i < 4; i++) {
            const int R0 = m0 + wm * 64 + i * 16 + rbase;
            if (EPI == EPI_F8) {
                u8* C = (u8*)C0 + z * bsC;
                *(u32*)(C + (long long)Cq * ldC + R0) =
                    pack_f8x4(acc[i][j][0] * alpha, acc[i][j][1] * alpha,
                              acc[i][j][2] * alpha, acc[i][j][3] * alpha);
            } else if (EPI == EPI_PV) {
                u8* C = (u8*)C0 + z * bsC;
                float v[4];
#pragma unroll
                for (int r = 0; r < 4; r++) {
                    float t = acc[i][j][r] * inv;
                    v[r] = (t / (1.f + __expf(-t))) * beta;   // silu * beta
                }
                *(u32*)(C + (long long)Cq * ldC + R0) =
                    pack_f8x4(v[0], v[1], v[2], v[3]);
            } else { // EPI_RV: A-rows 0..1023 -> R (alpha), 1024.. -> V^T (beta)
                const int seg = R0 >> 10;
                const int db = R0 & 1023;
                if (seg == 1) {
                    // V^T[bb][d][token], byte scatter over 4 d-rows
                    const int bb = Cq >> 11, tt = Cq & 2047;
                    u8* VTp = (u8*)C2;
#pragma unroll
                    for (int r = 0; r < 4; r++)
                        VTp[(long long)bb * (1024LL * 2048) +
                            (long long)(db + r) * 2048 + tt] =
                            cvt_f8(acc[i][j][r] * beta);
                } else {
                    u8* C = (u8*)C0;
                    *(u32*)(C + (long long)Cq * 1024 + db) =
                        pack_f8x4(acc[i][j][0] * alpha, acc[i][j][1] * alpha,
                                  acc[i][j][2] * alpha, acc[i][j][3] * alpha);
                }
            }
        }
    }
}

// x (8192 blocks, scale 8) + wv1|wv2|fc1|fc2 (1024 blocks each, scale 256)
// -> fp8; blocks 0..23 zero the 3 rsum buffers (24576 floats at rz).
__global__ __launch_bounds__(256) void convert_all(
    const float* x, const float* wv1, const float* wv2, const float* fc1,
    const float* fc2, u8* __restrict__ ax, u8* __restrict__ bproj,
    u8* __restrict__ wfc, float* __restrict__ rz)
{
    const int bid = blockIdx.x;
    if (bid < 24) {
        float4 zero = {0.f, 0.f, 0.f, 0.f};
        *(float4*)(rz + ((long long)bid * 256 + threadIdx.x) * 4) = zero;
    }
    const float* src;
    u8* dst;
    float scale;
    long long i;
    if (bid < 8192) {
        src = x; dst = ax; scale = 8.f;
        i = ((long long)bid * 256 + threadIdx.x) * 4;
    } else {
        const int idx = bid - 8192;
        const int wi = idx >> 10;
        const float* srcs[4] = {wv1, wv2, fc1, fc2};
        // wv1 -> Bproj[0] rows 1024+, wv2 -> Bproj[1] rows 1024+, fc -> Wfc
        u8* dsts[4] = {bproj + (1 << 20), bproj + 3 * (1 << 20),
                       wfc, wfc + (1 << 20)};
        src = srcs[wi]; dst = dsts[wi]; scale = 256.f;
        i = (((long long)(idx & 1023)) * 256 + threadIdx.x) * 4;
    }
    float4 v = *(const float4*)(src + i);
    *(u32*)(dst + i) = pack_f8x4(v.x * scale, v.y * scale,
                                 v.z * scale, v.w * scale);
}

// Transpose+convert wq1,wk1,wq2,wk2 (fp32 [1024][1024]) -> fp8^T * 256.
// Grid (256, 4); block handles a 64x64 tile; thread: 4x4 micro-tile.
__global__ __launch_bounds__(256) void convert_t(
    const float* wq1, const float* wk1, const float* wq2, const float* wk2,
    u8* __restrict__ o)
{
    const float* srcs[4] = {wq1, wk1, wq2, wk2};
    const float* src = srcs[blockIdx.y];
    u8* dst = o + (long long)blockIdx.y * (1 << 20);
    const int q0 = (blockIdx.x & 15) * 64, d0 = (blockIdx.x >> 4) * 64;
    const int qq = (threadIdx.x & 15) * 4, dd = (threadIdx.x >> 4) * 4;
    float4 v[4];
#pragma unroll
    for (int s = 0; s < 4; s++)
        v[s] = *(const float4*)(src + (long long)(q0 + qq + s) * 1024 + d0 + dd);
    const float* vf = (const float*)v;   // vf[s*4 + r]
#pragma unroll
    for (int r = 0; r < 4; r++)
        *(u32*)(dst + (long long)(d0 + dd + r) * 1024 + q0 + qq) =
            pack_f8x4(vf[0 * 4 + r] * 256.f, vf[1 * 4 + r] * 256.f,
                      vf[2 * 4 + r] * 256.f, vf[3 * 4 + r] * 256.f);
}

// out[row][c] = e[row][c] / rsum[row]  (1024 cols, fp32)
__global__ __launch_bounds__(256) void normalize_1024(
    const float* __restrict__ e, const float* __restrict__ rsum,
    float* __restrict__ out)
{
    const long long row = blockIdx.x;
    const float inv = 1.0f / rsum[row];
    const float* p = e + row * 1024;
    float* o = out + row * 1024;
    float4 v = *(const float4*)(p + threadIdx.x * 4);
    float4 ov;
    ov.x = v.x * inv; ov.y = v.y * inv; ov.z = v.z * inv; ov.w = v.w * inv;
    *(float4*)(o + threadIdx.x * 4) = ov;
}

extern "C" void kernel_launch(void* const* d_in, const int* in_sizes, int n_in,
                              void* d_out, int out_size, void* d_ws, size_t ws_size,
                              hipStream_t stream)
{
    float* out = (float*)d_out;

    constexpr int Bt = 4, S = 2048, D = 1024;
    constexpr int M = Bt * S;                  // 8192
    const long long MD = (long long)M * D;     // 8,388,608
    const long long DD = (long long)D * D;
    const long long SD = (long long)S * D;
    const long long SS = (long long)S * S;

    // ws: Af 8MB | Bproj 2x2MB | WqT 4x1MB | Wfc 2x1MB | Rf 8MB | VT 8MB |
    // Pf 16MB | Hs 8MB | SC fp32 32MB | rsum0|1|2
    u8* Af = (u8*)d_ws;
    u8* Bproj = Af + MD;                 // [2][2048][1024]: WqkT | wv
    u8* WqT = Bproj + 2 * 2048 * 1024;   // wq1T | wk1T | wq2T | wk2T
    u8* Wfc = WqT + 4 * DD;              // fc1 | fc2
    u8* Rf = Wfc + 2 * DD;
    u8* VT = Rf + MD;
    u8* Pf = VT + MD;
    u8* Hs = Pf + (long long)Bt * SS;
    float* SC = (float*)(Hs + MD);
    float* rsum0 = SC + MD;
    float* rsum1 = rsum0 + M;
    float* rsum2 = rsum1 + M;

    const dim3 blk(256);

    const float SOFT = 0.08838834764831845f; // 1/sqrt(128)
    // scale-fold alphas (all pow2 exact):
    const float a_d1   = 1.f / 64.f;               // WqkT: 256*256 -> 1024
    const float a_R[2] = {1.f / 512.f, 1.f / 1024.f};  // R1: 8*1024->16; R2: 256*1024->256
    const float b_V[2] = {1.f / 256.f, 1.f / 64.f};    // V1: 8*256->8; V2: 256*256->1024
    const float a_qk[2] = {SOFT / 128.f, SOFT / 65536.f}; // R*act scales
    const float a_pv[2] = {2.0f, 1.f / 64.f};      // 16 / V-scale, then /rsum
    const float b_pv[2] = {256.f, 65536.f};        // Hs store scale
    const float a_fc[2] = {256.f / 65536.f, 1.f / 16777216.f};

    convert_all<<<dim3(12288), blk, 0, stream>>>(
        (const float*)d_in[0], (const float*)d_in[3], (const float*)d_in[7],
        (const float*)d_in[4], (const float*)d_in[8], Af, Bproj, Wfc, rsum0);
    convert_t<<<dim3(256, 4), blk, 0, stream>>>(
        (const float*)d_in[1], (const float*)d_in[2], (const float*)d_in[5],
        (const float*)d_in[6], WqT);
    // Bproj[z] rows 0..1023 = WqkT_z = P(A=wqT_z, B=wkT_z), stored scale 1024
    gemm_fp8<EPI_F8><<<dim3(8, 8, 2), blk, 0, stream>>>(
        WqT, WqT + DD, Bproj, nullptr, nullptr, D, D, D, D,
        2 * DD, 2 * DD, (long long)2048 * 1024, a_d1, 0.f);

    const dim3 grv(M / 128, 2048 / 128, 1);    // [R|V] projection (64,16)
    const dim3 gqk(S / 128, S / 128, Bt);      // scores: x = queries, y = keys
    const dim3 gpv(S / 128, D / 128, Bt);      // x = tokens, y = d-tiles
    const dim3 gw(M / 128, D / 128, 1);        // fc GEMMs (64,8)

    for (int layer = 0; layer < 2; layer++) {
        const u8* bp = Bproj + (long long)layer * 2048 * 1024;
        const u8* fc = Wfc + (long long)layer * DD;
        float* rsum = layer ? rsum1 : rsum0;

        // R[t][j] (Rf, packed u32) and V^T[b][d][t] (VT, scatter)
        gemm_fp8<EPI_RV><<<grv, blk, 0, stream>>>(
            bp, Af, Rf, nullptr, VT, D, D, D, D, 0, 0, 0,
            a_R[layer], b_V[layer]);
        // P[z][q][key] = fp8(exp(score)/16); rsum[q] = sum exp.
        // keys side = activations themselves (Af), queries side = R.
        gemm_fp8<EPI_EXP><<<gqk, blk, 0, stream>>>(
            Af, Rf, Pf, rsum, nullptr, D, D, D, S, SD, SD, SS,
            a_qk[layer], 0.f);
        // Hs[token][d] = fp8(silu(P@V / rsum) * b_pv)
        gemm_fp8<EPI_PV><<<gpv, blk, 0, stream>>>(
            VT, Pf, Hs, rsum, nullptr, S, S, S, D,
            (long long)D * S, SS, SD, a_pv[layer], b_pv[layer]);
        if (layer == 0) {
            gemm_fp8<EPI_F8><<<gw, blk, 0, stream>>>(
                fc, Hs, Af, nullptr, nullptr, D, D, D, D, 0, 0, 0,
                a_fc[0], 0.f);
        } else {
            gemm_fp8<EPI_EXPF32><<<gw, blk, 0, stream>>>(
                fc, Hs, SC, rsum2, nullptr, D, D, D, D, 0, 0, 0,
                a_fc[1], 0.f);
        }
    }

    normalize_1024<<<dim3(M), blk, 0, stream>>>(SC, rsum2, out);
}